// Round 1
// baseline (313.413 us; speedup 1.0000x reference)
//
#include <hip/hip_runtime.h>

// out[b, i*16+j, d, l] = sum_ks s[b,(j-i)&15,l,ks] * t[b,j,l,d-ks], d in [0,125); 0 for d>=125.
// B=32, N=16, L=64, D_in=63, D_out=128. Output 32*256*128*64 fp32 = 256 MB.
//
// One wave (64 threads) per (b,i,j). lane = l so stores over l are coalesced
// (256 B per dword-store instruction). Each lane keeps its 63-float s row and
// t row in registers (static indices -> no scratch), conv fully unrolled:
// exactly 63*63 = 3969 v_fma_f32 per lane. d handled in 8 chunks of 16
// independent accumulators so FMAs issue back-to-back.

#define D_IN 63
#define L_DIM 64
#define N_DIM 16
#define DP 128

__global__ __launch_bounds__(64) void conv_kernel(
    const float* __restrict__ s, const float* __restrict__ t,
    float* __restrict__ out)
{
    const int blk = blockIdx.x;          // b*256 + i*16 + j
    const int b  = blk >> 8;
    const int ij = blk & 255;
    const int i  = ij >> 4;
    const int j  = ij & 15;
    const int k  = (j - i) & 15;
    const int l  = threadIdx.x;          // 0..63

    const float* __restrict__ srow = s + ((((size_t)b * N_DIM + k) * L_DIM + l) * D_IN);
    const float* __restrict__ trow = t + ((((size_t)b * N_DIM + j) * L_DIM + l) * D_IN);

    float sv[D_IN], tv[D_IN];
#pragma unroll
    for (int c = 0; c < D_IN; ++c) sv[c] = srow[c];
#pragma unroll
    for (int c = 0; c < D_IN; ++c) tv[c] = trow[c];

    float* __restrict__ orow = out + ((size_t)blk * (DP * L_DIM)) + l;

#pragma unroll
    for (int d0 = 0; d0 < DP; d0 += 16) {
        float acc[16];
#pragma unroll
        for (int dd = 0; dd < 16; ++dd) acc[dd] = 0.0f;

#pragma unroll
        for (int ks = 0; ks < D_IN; ++ks) {
#pragma unroll
            for (int dd = 0; dd < 16; ++dd) {
                const int kt = d0 + dd - ks;           // compile-time constant
                if (kt >= 0 && kt < D_IN)
                    acc[dd] += sv[ks] * tv[kt];
            }
        }

#pragma unroll
        for (int dd = 0; dd < 16; ++dd)
            orow[(size_t)(d0 + dd) * L_DIM] = acc[dd];
    }
}

extern "C" void kernel_launch(void* const* d_in, const int* in_sizes, int n_in,
                              void* d_out, int out_size, void* d_ws, size_t ws_size,
                              hipStream_t stream) {
    const float* s = (const float*)d_in[0];
    const float* t = (const float*)d_in[1];
    float* out = (float*)d_out;
    // grid = B * N * N = 32 * 16 * 16 = 8192 waves
    hipLaunchKernelGGL(conv_kernel, dim3(32 * N_DIM * N_DIM), dim3(64), 0, stream,
                       s, t, out);
}